// Round 4
// baseline (4999.017 us; speedup 1.0000x reference)
//
#include <hip/hip_runtime.h>
#include <hip/hip_bf16.h>

#define B_  128
#define P_  196
#define ENCD 2048
#define A_  512
#define E_  512
#define D_  512
#define V_  10000
#define L_  22
#define T_  21
#define VPAD 10112   // 79*128
#define NBLK 256

typedef __attribute__((ext_vector_type(8))) short short8;
typedef __attribute__((ext_vector_type(4))) float f32x4;

static __device__ __forceinline__ float bf2f(unsigned short u){
  union { unsigned int i; float f; } x; x.i = ((unsigned int)u) << 16; return x.f;
}
static __device__ __forceinline__ unsigned short f2bf(float f){
  union { float f; unsigned int i; } x; x.f = f;
  unsigned int r = x.i + 0x7fffu + ((x.i >> 16) & 1u);
  return (unsigned short)(r >> 16);
}
static __device__ __forceinline__ unsigned int pack2(float a, float b){
  return (unsigned int)f2bf(a) | ((unsigned int)f2bf(b) << 16);
}
static __device__ __forceinline__ void glds16(const void* g, void* l){
  __builtin_amdgcn_global_load_lds((const __attribute__((address_space(1))) void*)g,
                                   (__attribute__((address_space(3))) void*)l, 16, 0, 0);
}

// Grid barrier: monotonic counter, agent-scope atomics. No reset -> no race.
// Safe because all NBLK blocks are co-resident (256 blocks, 1+/CU, stream
// is drained before this kernel starts).
static __device__ __forceinline__ void gridbar(int* cnt, int target){
  __syncthreads();
  if (threadIdx.x == 0){
    __threadfence();   // release prior writes to device scope
    __hip_atomic_fetch_add(cnt, 1, __ATOMIC_ACQ_REL, __HIP_MEMORY_SCOPE_AGENT);
    while (__hip_atomic_load(cnt, __ATOMIC_ACQUIRE, __HIP_MEMORY_SCOPE_AGENT) < target)
      __builtin_amdgcn_s_sleep(2);
    __threadfence();   // acquire other agents' writes
  }
  __syncthreads();
}

// ---------------------------------------------------------------------------
// 128x128-tile GEMM: C[M,N] = A[M,K] @ B[N,K]^T (+bias). bf16 in, f32 acc.
// Double-buffered LDS, one barrier per K-step.
// ---------------------------------------------------------------------------
__global__ __launch_bounds__(256) void gemm128(
    const unsigned short* __restrict__ A, int lda,
    const unsigned short* __restrict__ B, int ldb, int K,
    const float* __restrict__ bias,
    float* __restrict__ outF, long ldo,
    unsigned short* __restrict__ outB, long ldob,
    int ntiles)
{
  __shared__ unsigned short As[2][128*32];
  __shared__ unsigned short Bs[2][128*32];
  int bid = blockIdx.x, nblk = gridDim.x;
  if ((nblk & 7) == 0){ int per = nblk >> 3; bid = (bid & 7)*per + (bid >> 3); }
  int nt = bid % ntiles, mt = bid / ntiles;
  int tid = threadIdx.x, wave = tid >> 6, lane = tid & 63;
  int quad = lane >> 4, l16 = lane & 15;

  const unsigned short* ga = A + (size_t)(mt*128 + wave*32 + (lane>>2))*lda + (lane&3)*8;
  const unsigned short* gb = B + (size_t)(nt*128 + wave*32 + (lane>>2))*ldb + (lane&3)*8;

  int wm = wave >> 1, wn = wave & 1;

  auto STAGE = [&](int buf, int kk){
    unsigned short* la = &As[buf][wave*1024];
    unsigned short* lb = &Bs[buf][wave*1024];
    glds16(ga + kk,                  la);
    glds16(ga + kk + (size_t)16*lda, la + 512);
    glds16(gb + kk,                  lb);
    glds16(gb + kk + (size_t)16*ldb, lb + 512);
  };

  f32x4 acc[4][4];
  #pragma unroll
  for (int i=0;i<4;++i)
    #pragma unroll
    for (int j=0;j<4;++j) acc[i][j] = (f32x4){0.f,0.f,0.f,0.f};

  STAGE(0, 0);
  int cur = 0;
  for (int k=0; k<K; k+=32){
    __syncthreads();
    if (k+32 < K) STAGE(cur^1, k+32);
    const unsigned short* rA = &As[cur][(wm*64 + l16)*32 + quad*8];
    const unsigned short* rB = &Bs[cur][(wn*64 + l16)*32 + quad*8];
    short8 af[4], bfr[4];
    #pragma unroll
    for (int i=0;i<4;++i) af[i]  = *(const short8*)(rA + i*16*32);
    #pragma unroll
    for (int i=0;i<4;++i) bfr[i] = *(const short8*)(rB + i*16*32);
    #pragma unroll
    for (int mf=0;mf<4;++mf)
      #pragma unroll
      for (int nf=0;nf<4;++nf)
        acc[mf][nf] = __builtin_amdgcn_mfma_f32_16x16x32_bf16(af[mf], bfr[nf], acc[mf][nf], 0,0,0);
    cur ^= 1;
  }

  #pragma unroll
  for (int mf=0;mf<4;++mf){
    long mbase = mt*128 + wm*64 + mf*16 + quad*4;
    #pragma unroll
    for (int nf=0;nf<4;++nf){
      int col = nt*128 + wn*64 + nf*16 + l16;
      float bv = bias ? bias[col] : 0.f;
      #pragma unroll
      for (int r=0;r<4;++r){
        float v = acc[mf][nf][r] + bv;
        long m = mbase + r;
        if (outF) outF[m*ldo + col] = v;
        if (outB) outB[m*ldob + col] = f2bf(v);
      }
    }
  }
}

// ---------------------------------------------------------------------------
// Compacted preds GEMM: A = h_cmp [NR, 512], B = Wfc padded.
// ---------------------------------------------------------------------------
__global__ __launch_bounds__(256) void gemm_preds(
    const unsigned short* __restrict__ A,
    const unsigned short* __restrict__ B,
    const float* __restrict__ bias,
    const int* __restrict__ rs,
    const int* __restrict__ trow, const int* __restrict__ brow,
    float* __restrict__ out)
{
  __shared__ unsigned short As[2][128*32];
  __shared__ unsigned short Bs[2][128*32];
  int nt = blockIdx.x % 79, mt = blockIdx.x / 79;
  int NR = rs[T_];
  if (mt*128 >= NR) return;
  int tid = threadIdx.x, wave = tid >> 6, lane = tid & 63;
  int quad = lane >> 4, l16 = lane & 15;

  const unsigned short* ga = A + (size_t)(mt*128 + wave*32 + (lane>>2))*D_ + (lane&3)*8;
  const unsigned short* gb = B + (size_t)(nt*128 + wave*32 + (lane>>2))*D_ + (lane&3)*8;

  int wm = wave >> 1, wn = wave & 1;

  auto STAGE = [&](int buf, int kk){
    unsigned short* la = &As[buf][wave*1024];
    unsigned short* lb = &Bs[buf][wave*1024];
    glds16(ga + kk,                 la);
    glds16(ga + kk + (size_t)16*D_, la + 512);
    glds16(gb + kk,                 lb);
    glds16(gb + kk + (size_t)16*D_, lb + 512);
  };

  f32x4 acc[4][4];
  #pragma unroll
  for (int i=0;i<4;++i)
    #pragma unroll
    for (int j=0;j<4;++j) acc[i][j] = (f32x4){0.f,0.f,0.f,0.f};

  STAGE(0, 0);
  int cur = 0;
  for (int k=0; k<D_; k+=32){
    __syncthreads();
    if (k+32 < D_) STAGE(cur^1, k+32);
    const unsigned short* rA = &As[cur][(wm*64 + l16)*32 + quad*8];
    const unsigned short* rB = &Bs[cur][(wn*64 + l16)*32 + quad*8];
    short8 af[4], bfr[4];
    #pragma unroll
    for (int i=0;i<4;++i) af[i]  = *(const short8*)(rA + i*16*32);
    #pragma unroll
    for (int i=0;i<4;++i) bfr[i] = *(const short8*)(rB + i*16*32);
    #pragma unroll
    for (int mf=0;mf<4;++mf)
      #pragma unroll
      for (int nf=0;nf<4;++nf)
        acc[mf][nf] = __builtin_amdgcn_mfma_f32_16x16x32_bf16(af[mf], bfr[nf], acc[mf][nf], 0,0,0);
    cur ^= 1;
  }

  #pragma unroll
  for (int mf=0;mf<4;++mf){
    int mbase = mt*128 + wm*64 + mf*16 + quad*4;
    #pragma unroll
    for (int nf=0;nf<4;++nf){
      int col = nt*128 + wn*64 + nf*16 + l16;
      if (col >= V_) continue;
      float bv = bias[col];
      #pragma unroll
      for (int r=0;r<4;++r){
        int row = mbase + r;
        if (row >= NR) continue;
        int tt = trow[row], bb = brow[row];
        out[(size_t)(bb*T_ + tt)*V_ + col] = acc[mf][nf][r] + bv;
      }
    }
  }
}

// ---------------------------------------------------------------------------
// Persistent decode kernel: all 21 steps in ONE launch, 256 blocks x 512
// threads, software grid barrier (2 per step). Phase bodies identical to
// the previous per-step kernels.
// ---------------------------------------------------------------------------
__global__ __launch_bounds__(512) void decode_persist(
    float* __restrict__ h,
    const unsigned short* __restrict__ WdaT,     // [D][A] bf16
    const float* __restrict__ bda,
    const unsigned short* __restrict__ att1,     // [B*P, A] bf16
    const float* __restrict__ wfull, const float* __restrict__ bfull,
    const unsigned short* __restrict__ enc_bf,   // [B,P,ENC] bf16
    const unsigned short* __restrict__ Whh,      // [2048][512] bf16
    const unsigned short* __restrict__ Wienc,    // [2048][2048] bf16
    const float* __restrict__ gates_pre,         // [B,T,2048] f32
    float* __restrict__ c,
    unsigned short* __restrict__ h_bf_all,       // [(T+1),B,D]
    unsigned short* __restrict__ h_cmp,          // [NR,D]
    unsigned short* __restrict__ awe_bf,         // [B,ENC]
    const int* __restrict__ actv, const int* __restrict__ rs,
    float* __restrict__ out_alphas,              // [T,...] base (stride T*P per b)
    int* __restrict__ barcnt)
{
  __shared__ float hs[D_];
  __shared__ float att2p[1024];
  __shared__ float att2s[A_];
  __shared__ float wfs[A_];
  __shared__ float als[256];
  __shared__ float red[16];
  __shared__ float reds[8*1024];   // 32 KB (gates reduce)

  int bid = blockIdx.x, tid = threadIdx.x;
  int wave = tid >> 6, lane = tid & 63;
  int quad = lane >> 4, l16 = lane & 15;
  int b = bid >> 1, j = bid & 1;                 // phase A mapping
  int ntg = (bid & 7)*4 + ((bid >> 3) & 3);      // phase B: XCD-grouped nt
  int mtg = bid >> 5;
  int m0 = mtg*16;
  int target = 0;

  if (tid < 128) ((float4*)wfs)[tid] = ((const float4*)wfull)[tid];
  float bf0 = bfull[0];

  for (int t = 0; t < T_; ++t){
    int nact = actv[t];
    float* out_alpha = out_alphas + (size_t)t*P_;

    // ================= Phase A: attention =================
    if (b < nact){
      if (tid < 128) ((float4*)hs)[tid] = ((const float4*)(h + (size_t)b*D_))[tid];
      __syncthreads();

      { // att2 = h @ Wda^T, split-K over thread halves, 2 cols/thr
        int half = tid >> 8, ap = tid & 255;
        const unsigned int* wp = (const unsigned int*)WdaT + (size_t)half*256*256 + ap;
        const float* hh = hs + half*256;
        float s0 = 0.f, s1 = 0.f;
        #pragma unroll 4
        for (int k=0;k<256;++k){
          unsigned int v = wp[(size_t)k*256];
          float hk = hh[k];
          s0 = fmaf(bf2f((unsigned short)(v & 0xffffu)), hk, s0);
          s1 = fmaf(bf2f((unsigned short)(v >> 16)),     hk, s1);
        }
        att2p[half*512 + ap*2]     = s0;
        att2p[half*512 + ap*2 + 1] = s1;
      }
      __syncthreads();
      if (tid < A_) att2s[tid] = att2p[tid] + att2p[512 + tid] + bda[tid];
      __syncthreads();

      // e[p] = relu(att1[p]+att2) . wfull  (8 waves over P rows)
      for (int p = wave; p < P_; p += 8){
        short8 v = *(const short8*)(att1 + ((size_t)(b*P_ + p))*A_ + lane*8);
        float4 a20 = *(const float4*)(att2s + lane*8);
        float4 a21 = *(const float4*)(att2s + lane*8 + 4);
        float4 wf0 = *(const float4*)(wfs + lane*8);
        float4 wf1 = *(const float4*)(wfs + lane*8 + 4);
        float s = 0.f;
        s += fmaxf(bf2f((unsigned short)v[0]) + a20.x, 0.f) * wf0.x;
        s += fmaxf(bf2f((unsigned short)v[1]) + a20.y, 0.f) * wf0.y;
        s += fmaxf(bf2f((unsigned short)v[2]) + a20.z, 0.f) * wf0.z;
        s += fmaxf(bf2f((unsigned short)v[3]) + a20.w, 0.f) * wf0.w;
        s += fmaxf(bf2f((unsigned short)v[4]) + a21.x, 0.f) * wf1.x;
        s += fmaxf(bf2f((unsigned short)v[5]) + a21.y, 0.f) * wf1.y;
        s += fmaxf(bf2f((unsigned short)v[6]) + a21.z, 0.f) * wf1.z;
        s += fmaxf(bf2f((unsigned short)v[7]) + a21.w, 0.f) * wf1.w;
        #pragma unroll
        for (int off=32; off; off>>=1) s += __shfl_xor(s, off, 64);
        if (lane == 0) als[p] = s + bf0;
      }
      __syncthreads();

      // softmax over 196
      float ev = (tid < P_) ? als[tid] : -1e30f;
      float mx = ev;
      #pragma unroll
      for (int off=32; off; off>>=1) mx = fmaxf(mx, __shfl_xor(mx, off, 64));
      if (lane == 0) red[wave] = mx;
      __syncthreads();
      float bmax = fmaxf(fmaxf(fmaxf(red[0],red[1]), fmaxf(red[2],red[3])),
                         fmaxf(fmaxf(red[4],red[5]), fmaxf(red[6],red[7])));
      float ex = (tid < P_) ? __expf(ev - bmax) : 0.f;
      float sm = ex;
      #pragma unroll
      for (int off=32; off; off>>=1) sm += __shfl_xor(sm, off, 64);
      if (lane == 0) red[8 + wave] = sm;
      __syncthreads();
      float inv = 1.f / (red[8]+red[9]+red[10]+red[11]+red[12]+red[13]+red[14]+red[15]);
      if (tid < P_){
        float alpha = ex * inv;
        als[tid] = alpha;
        if (j == 0) out_alpha[(size_t)b*(T_*(long)P_) + tid] = alpha;
      }
      __syncthreads();

      // awe = alpha . enc, column-half j
      {
        int cu = j*512 + tid;
        const unsigned int* ep = (const unsigned int*)enc_bf + (size_t)b*P_*1024 + cu;
        float a0 = 0.f, a1 = 0.f;
        for (int p=0; p<P_; p+=2){
          unsigned int v0 = ep[(size_t)(p+0)*1024];
          unsigned int v1 = ep[(size_t)(p+1)*1024];
          float x0 = als[p], x1 = als[p+1];
          a0 = fmaf(bf2f((unsigned short)(v0 & 0xffffu)), x0, a0);
          a1 = fmaf(bf2f((unsigned short)(v0 >> 16)),     x0, a1);
          a0 = fmaf(bf2f((unsigned short)(v1 & 0xffffu)), x1, a0);
          a1 = fmaf(bf2f((unsigned short)(v1 >> 16)),     x1, a1);
        }
        ((unsigned int*)awe_bf)[(size_t)b*1024 + cu] = pack2(a0, a1);
      }
    } else {
      if (j == 0 && tid < P_) out_alpha[(size_t)b*(T_*(long)P_) + tid] = 0.f;
    }

    target += NBLK; gridbar(barcnt, target);

    // ================= Phase B: gates GEMM + LSTM pointwise =================
    const unsigned short* hbf = h_bf_all + (size_t)t*B_*D_;
    unsigned short* hbf_out   = h_bf_all + (size_t)(t+1)*B_*D_;

    if (m0 >= nact){
      // frozen tile: propagate hbf
      if (tid < 256){
        int mi = tid >> 4, di = tid & 15;
        int idx = (m0 + mi)*512 + ntg*16 + di;
        hbf_out[idx] = hbf[idx];
      }
    } else {
      int ks = wave*320, ke = ks + 320;      // Ktot = 512 + 2048 over 8 waves
      f32x4 acc[4];
      #pragma unroll
      for (int f=0;f<4;++f) acc[f] = (f32x4){0.f,0.f,0.f,0.f};

      for (int kk=ks; kk<ke; kk+=32){
        const unsigned short* Ap; const unsigned short* Bp; int k, lda2, ldb2;
        if (kk < 512){ Ap = hbf;    Bp = Whh;   k = kk;       lda2 = 512;  ldb2 = 512;  }
        else         { Ap = awe_bf; Bp = Wienc; k = kk - 512; lda2 = 2048; ldb2 = 2048; }
        short8 a = *(const short8*)(Ap + (size_t)(m0 + l16)*lda2 + k + quad*8);
        #pragma unroll
        for (int f=0;f<4;++f){
          short8 bb = *(const short8*)(Bp + (size_t)(ntg*16 + f*512 + l16)*ldb2 + k + quad*8);
          acc[f] = __builtin_amdgcn_mfma_f32_16x16x32_bf16(a, bb, acc[f], 0,0,0);
        }
      }
      {
        float* dst = &reds[wave*1024 + lane*16];
        #pragma unroll
        for (int f=0;f<4;++f) ((f32x4*)dst)[f] = acc[f];
      }
      __syncthreads();
      if (tid < 256){
        int mi = tid >> 4, di = tid & 15;
        int m = m0 + mi, d = ntg*16 + di;
        int rl = ((mi>>2)*16 + di)*16 + (mi&3);   // lane*16 + r
        float g4[4];
        #pragma unroll
        for (int f=0;f<4;++f){
          float s = 0.f;
          #pragma unroll
          for (int w=0;w<8;++w) s += reds[w*1024 + rl + f*4];
          g4[f] = s;
        }
        const float* gp = gates_pre + ((size_t)m*T_ + t)*2048;
        float vi = g4[0] + gp[d];
        float vf = g4[1] + gp[512 + d];
        float vg = g4[2] + gp[1024 + d];
        float vo = g4[3] + gp[1536 + d];
        float si = 1.f/(1.f + __expf(-vi));
        float sf = 1.f/(1.f + __expf(-vf));
        float so = 1.f/(1.f + __expf(-vo));
        float tg = tanhf(vg);
        int idx = m*512 + d;
        float cn = sf*c[idx] + si*tg;
        float hn = so*tanhf(cn);
        bool act = m < nact;
        float h2 = act ? hn : h[idx];
        float c2 = act ? cn : c[idx];
        h[idx] = h2; c[idx] = c2;
        unsigned short hb = f2bf(h2);
        hbf_out[idx] = hb;
        if (act) h_cmp[(size_t)(rs[t] + m)*512 + d] = hb;
      }
      __syncthreads();   // reds reused next iteration
    }

    target += NBLK; gridbar(barcnt, target);
  }
}

// ---- active-prefix bookkeeping (also zeroes the grid-barrier counter) ----
__global__ __launch_bounds__(256) void calc_active(
    const int* __restrict__ lens, int* __restrict__ actv,
    int* __restrict__ rs, int* __restrict__ trow, int* __restrict__ brow,
    int* __restrict__ barcnt)
{
  __shared__ int scnt[T_];
  __shared__ int srs[T_+1];
  int tid = threadIdx.x;
  if (tid == 0) barcnt[0] = 0;
  if (tid < T_){
    int cnt = 0;
    for (int b=0;b<B_;++b) cnt += ((lens[b]-1) > tid) ? 1 : 0;
    scnt[tid] = cnt; actv[tid] = cnt;
  }
  __syncthreads();
  if (tid == 0){
    int s = 0;
    for (int t=0;t<T_;++t){ srs[t] = s; rs[t] = s; s += scnt[t]; }
    srs[T_] = s; rs[T_] = s;
  }
  __syncthreads();
  int NR = srs[T_];
  for (int r = tid; r < NR; r += 256){
    int t = 0;
    while (r >= srs[t+1]) ++t;
    trow[r] = t; brow[r] = r - srs[t];
  }
}

// zero preds rows for inactive (b,t)
__global__ __launch_bounds__(256) void zero_inactive(
    const int* __restrict__ lens, float* __restrict__ out)
{
  int bid = blockIdx.x;
  int b = bid / T_, t = bid - b*T_;
  if ((lens[b]-1) > t) return;
  float4* o = (float4*)(out + (size_t)(b*T_ + t)*V_);
  float4 z = {0.f,0.f,0.f,0.f};
  for (int i = threadIdx.x; i < V_/4; i += 256) o[i] = z;
}

// ---- one-time helpers ----
__global__ __launch_bounds__(256) void enc_cvt_mean(
    const float* __restrict__ enc, unsigned short* __restrict__ enc_bf,
    unsigned short* __restrict__ mean_bf)
{
  int b = blockIdx.x >> 1;
  int c = (blockIdx.x & 1)*1024 + threadIdx.x*4;
  size_t base = (size_t)b*P_*ENCD + c;
  float s0=0.f,s1=0.f,s2=0.f,s3=0.f;
  for (int p=0; p<P_; p+=2){
    float4 v0 = *(const float4*)(enc + base + (size_t)(p+0)*ENCD);
    float4 v1 = *(const float4*)(enc + base + (size_t)(p+1)*ENCD);
    s0 += v0.x + v1.x; s1 += v0.y + v1.y; s2 += v0.z + v1.z; s3 += v0.w + v1.w;
    uint2 r0; r0.x = pack2(v0.x, v0.y); r0.y = pack2(v0.z, v0.w);
    uint2 r1; r1.x = pack2(v1.x, v1.y); r1.y = pack2(v1.z, v1.w);
    *(uint2*)(enc_bf + base + (size_t)(p+0)*ENCD) = r0;
    *(uint2*)(enc_bf + base + (size_t)(p+1)*ENCD) = r1;
  }
  const float is = 1.f/196.f;
  uint2 m; m.x = pack2(s0*is, s1*is); m.y = pack2(s2*is, s3*is);
  *(uint2*)(mean_bf + (size_t)b*ENCD + c) = m;
}

__global__ __launch_bounds__(256) void cvt_bf16(
    const float* __restrict__ in, unsigned short* __restrict__ out, int n4)
{
  int i = blockIdx.x*256 + threadIdx.x;
  if (i < n4){
    float4 v = ((const float4*)in)[i];
    uint2 o; o.x = pack2(v.x, v.y); o.y = pack2(v.z, v.w);
    ((uint2*)out)[i] = o;
  }
}

__global__ __launch_bounds__(256) void cvt_T_512(
    const float* __restrict__ W, unsigned short* __restrict__ WT)
{
  int a = blockIdx.x;
  for (int k = threadIdx.x; k < 512; k += 256)
    WT[(size_t)k*512 + a] = f2bf(W[(size_t)a*512 + k]);
}

__global__ __launch_bounds__(256) void split_wih(
    const float* __restrict__ W, unsigned short* __restrict__ Wemb,
    unsigned short* __restrict__ Wenc)
{
  int j = blockIdx.x;
  for (int k4 = threadIdx.x; k4 < 640; k4 += 256){
    float4 v = *(const float4*)(W + (size_t)j*2560 + k4*4);
    uint2 o; o.x = pack2(v.x, v.y); o.y = pack2(v.z, v.w);
    if (k4 < 128) *(uint2*)(Wemb + (size_t)j*512  + k4*4)        = o;
    else          *(uint2*)(Wenc + (size_t)j*2048 + (k4-128)*4)  = o;
  }
}

__global__ void add_bias2(const float* __restrict__ a, const float* __restrict__ b,
                          float* __restrict__ out, int n)
{
  int i = blockIdx.x*256 + threadIdx.x;
  if (i < n) out[i] = a[i] + b[i];
}

__global__ __launch_bounds__(128) void gather_emb(
    const int* __restrict__ caps, const float* __restrict__ E,
    unsigned short* __restrict__ X)
{
  int r = blockIdx.x;
  int b = r / T_, t = r - b*T_;
  int tok = caps[b*L_ + t];
  int c = threadIdx.x*4;
  float4 v = *(const float4*)(E + (size_t)tok*E_ + c);
  uint2 o; o.x = pack2(v.x, v.y); o.y = pack2(v.z, v.w);
  *(uint2*)(X + (size_t)r*E_ + c) = o;
}

// ---------------------------------------------------------------------------
extern "C" void kernel_launch(void* const* d_in, const int* in_sizes, int n_in,
                              void* d_out, int out_size, void* d_ws, size_t ws_size,
                              hipStream_t stream)
{
  const float* enc   = (const float*)d_in[0];
  const int*   caps  = (const int*)d_in[1];
  const int*   lens  = (const int*)d_in[2];
  const float* Eemb  = (const float*)d_in[3];
  const float* Wea   = (const float*)d_in[4];
  const float* bea   = (const float*)d_in[5];
  const float* Wda   = (const float*)d_in[6];
  const float* bda   = (const float*)d_in[7];
  const float* wfull = (const float*)d_in[8];
  const float* bfull = (const float*)d_in[9];
  const float* Wih0  = (const float*)d_in[10];
  const float* bih0  = (const float*)d_in[11];
  const float* Wic0  = (const float*)d_in[12];
  const float* bic0  = (const float*)d_in[13];
  const float* Wih   = (const float*)d_in[14];
  const float* bih   = (const float*)d_in[15];
  const float* Whh   = (const float*)d_in[16];
  const float* bhh   = (const float*)d_in[17];
  const float* Wfc   = (const float*)d_in[18];
  const float* bfc   = (const float*)d_in[19];

  char* wsp = (char*)d_ws;
  auto carve = [&](size_t bytes) -> char* {
    char* p = wsp; wsp += (bytes + 255) & ~(size_t)255; return p;
  };
  unsigned short* enc_bf   = (unsigned short*)carve((size_t)B_*P_*ENCD*2);
  unsigned short* att1_bf  = (unsigned short*)carve((size_t)B_*P_*A_*2);
  unsigned short* mean_bf  = (unsigned short*)carve((size_t)B_*ENCD*2);
  float*          gates_pre= (float*)carve((size_t)B_*T_*2048*4);
  unsigned short* X_emb    = (unsigned short*)carve((size_t)B_*T_*E_*2);
  unsigned short* Wea_bf   = (unsigned short*)carve((size_t)A_*ENCD*2);
  unsigned short* WdaT_bf  = (unsigned short*)carve((size_t)A_*D_*2);
  unsigned short* Wh0_bf   = (unsigned short*)carve((size_t)D_*ENCD*2);
  unsigned short* Wc0_bf   = (unsigned short*)carve((size_t)D_*ENCD*2);
  unsigned short* Whh_bf   = (unsigned short*)carve((size_t)2048*D_*2);
  unsigned short* Wie_bf   = (unsigned short*)carve((size_t)2048*E_*2);
  unsigned short* Wienc_bf = (unsigned short*)carve((size_t)2048*ENCD*2);
  unsigned short* Wfc_bf   = (unsigned short*)carve((size_t)VPAD*D_*2);
  float*          bias_ifgo= (float*)carve((size_t)2048*4);
  float*          h        = (float*)carve((size_t)B_*D_*4);
  float*          c        = (float*)carve((size_t)B_*D_*4);
  unsigned short* h_bf_all = (unsigned short*)carve((size_t)(T_+1)*B_*D_*2);
  unsigned short* h_cmp    = (unsigned short*)carve((size_t)T_*B_*D_*2);
  unsigned short* awe_bf   = (unsigned short*)carve((size_t)B_*ENCD*2);
  int*            actv     = (int*)carve(64*4);
  int*            rs       = (int*)carve(64*4);
  int*            trow     = (int*)carve((size_t)T_*B_*4);
  int*            brow     = (int*)carve((size_t)T_*B_*4);
  int*            barcnt   = (int*)carve(256);

  float* out_preds  = (float*)d_out;                       // [B, T, V]
  float* out_alphas = (float*)d_out + (size_t)B_*T_*V_;    // [B, T, P]

  // ---- one-time conversions / bookkeeping ----
  calc_active<<<1, 256, 0, stream>>>(lens, actv, rs, trow, brow, barcnt);
  zero_inactive<<<B_*T_, 256, 0, stream>>>(lens, out_preds);
  enc_cvt_mean<<<256, 256, 0, stream>>>(enc, enc_bf, mean_bf);
  cvt_bf16<<<1024, 256, 0, stream>>>(Wea,  Wea_bf, A_*ENCD/4);
  cvt_T_512<<<512, 256, 0, stream>>>(Wda, WdaT_bf);
  cvt_bf16<<<1024, 256, 0, stream>>>(Wih0, Wh0_bf, D_*ENCD/4);
  cvt_bf16<<<1024, 256, 0, stream>>>(Wic0, Wc0_bf, D_*ENCD/4);
  cvt_bf16<<<1024, 256, 0, stream>>>(Whh,  Whh_bf, 2048*D_/4);
  cvt_bf16<<<5000, 256, 0, stream>>>(Wfc,  Wfc_bf, V_*D_/4);
  split_wih<<<2048, 256, 0, stream>>>(Wih, Wie_bf, Wienc_bf);
  add_bias2<<<8, 256, 0, stream>>>(bih, bhh, bias_ifgo, 2048);
  gather_emb<<<B_*T_, 128, 0, stream>>>(caps, Eemb, X_emb);

  // ---- hoisted GEMMs ----
  gemm128<<<1*4, 256, 0, stream>>>(mean_bf, ENCD, Wh0_bf, ENCD, ENCD,
                                   bih0, h, D_, h_bf_all, D_, 4);          // h0 (slot 0)
  gemm128<<<1*4, 256, 0, stream>>>(mean_bf, ENCD, Wc0_bf, ENCD, ENCD,
                                   bic0, c, D_, (unsigned short*)0, 0, 4); // c0
  gemm128<<<196*4, 256, 0, stream>>>(enc_bf, ENCD, Wea_bf, ENCD, ENCD,
                                     bea, (float*)0, 0, att1_bf, A_, 4);   // att1
  gemm128<<<21*16, 256, 0, stream>>>(X_emb, E_, Wie_bf, E_, E_,
                                     bias_ifgo, gates_pre, 2048, (unsigned short*)0, 0, 16);

  // ---- decode loop: ONE persistent kernel, software grid barrier ----
  decode_persist<<<NBLK, 512, 0, stream>>>(
      h, WdaT_bf, bda, att1_bf, wfull, bfull, enc_bf,
      Whh_bf, Wienc_bf, gates_pre, c, h_bf_all, h_cmp, awe_bf,
      actv, rs, out_alphas, barcnt);

  // ---- compacted preds GEMM ----
  gemm_preds<<<21*79, 256, 0, stream>>>(h_cmp, Wfc_bf, bfc, rs, trow, brow,
                                        out_preds);
}

// Round 5
// 1724.347 us; speedup vs baseline: 2.8991x; 2.8991x over previous
//
#include <hip/hip_runtime.h>
#include <hip/hip_bf16.h>

#define B_  128
#define P_  196
#define ENCD 2048
#define A_  512
#define E_  512
#define D_  512
#define V_  10000
#define L_  22
#define T_  21
#define VPAD 10112   // 79*128

typedef __attribute__((ext_vector_type(8))) short short8;
typedef __attribute__((ext_vector_type(4))) float f32x4;

static __device__ __forceinline__ float bf2f(unsigned short u){
  union { unsigned int i; float f; } x; x.i = ((unsigned int)u) << 16; return x.f;
}
static __device__ __forceinline__ unsigned short f2bf(float f){
  union { float f; unsigned int i; } x; x.f = f;
  unsigned int r = x.i + 0x7fffu + ((x.i >> 16) & 1u);
  return (unsigned short)(r >> 16);
}
static __device__ __forceinline__ unsigned int pack2(float a, float b){
  return (unsigned int)f2bf(a) | ((unsigned int)f2bf(b) << 16);
}
static __device__ __forceinline__ void glds16(const void* g, void* l){
  __builtin_amdgcn_global_load_lds((const __attribute__((address_space(1))) void*)g,
                                   (__attribute__((address_space(3))) void*)l, 16, 0, 0);
}

// ---------------------------------------------------------------------------
// 128x128-tile GEMM: C[M,N] = A[M,K] @ B[N,K]^T (+bias). bf16 in, f32 acc.
// 3-buffer LDS pipeline with COUNTED vmcnt: 2 tiles always in flight across
// the barrier (never drain to 0 mid-loop). Each wave stages its own 32-row
// chunk; vmcnt(4) waits only for the oldest tile's 4 loads, then raw
// s_barrier aligns waves. Latency-bound regime -> ~2x vs drain-to-0.
// ---------------------------------------------------------------------------
__global__ __launch_bounds__(256) void gemm128(
    const unsigned short* __restrict__ A, int lda,
    const unsigned short* __restrict__ B, int ldb, int K,
    const float* __restrict__ bias,
    float* __restrict__ outF, long ldo,
    unsigned short* __restrict__ outB, long ldob,
    int ntiles)
{
  __shared__ unsigned short As[3][128*32];
  __shared__ unsigned short Bs[3][128*32];
  int bid = blockIdx.x, nblk = gridDim.x;
  if ((nblk & 7) == 0){ int per = nblk >> 3; bid = (bid & 7)*per + (bid >> 3); }
  int nt = bid % ntiles, mt = bid / ntiles;
  int tid = threadIdx.x, wave = tid >> 6, lane = tid & 63;
  int quad = lane >> 4, l16 = lane & 15;

  const unsigned short* ga = A + (size_t)(mt*128 + wave*32 + (lane>>2))*lda + (lane&3)*8;
  const unsigned short* gb = B + (size_t)(nt*128 + wave*32 + (lane>>2))*ldb + (lane&3)*8;

  int wm = wave >> 1, wn = wave & 1;

  auto STAGE = [&](int buf, int kk){
    unsigned short* la = &As[buf][wave*1024];
    unsigned short* lb = &Bs[buf][wave*1024];
    glds16(ga + kk,                  la);
    glds16(ga + kk + (size_t)16*lda, la + 512);
    glds16(gb + kk,                  lb);
    glds16(gb + kk + (size_t)16*ldb, lb + 512);
  };

  f32x4 acc[4][4];
  #pragma unroll
  for (int i=0;i<4;++i)
    #pragma unroll
    for (int j=0;j<4;++j) acc[i][j] = (f32x4){0.f,0.f,0.f,0.f};

  STAGE(0, 0);            // K >= 64 for all callers
  STAGE(1, 32);
  int cur = 0;
  for (int k=0; k<K; k+=32){
    if (k+32 < K) asm volatile("s_waitcnt vmcnt(4)" ::: "memory");
    else          asm volatile("s_waitcnt vmcnt(0)" ::: "memory");
    __builtin_amdgcn_s_barrier();
    __builtin_amdgcn_sched_barrier(0);
    if (k+64 < K) STAGE(cur==0 ? 2 : (cur==1 ? 0 : 1), k+64);
    const unsigned short* rA = &As[cur][(wm*64 + l16)*32 + quad*8];
    const unsigned short* rB = &Bs[cur][(wn*64 + l16)*32 + quad*8];
    short8 af[4], bfr[4];
    #pragma unroll
    for (int i=0;i<4;++i) af[i]  = *(const short8*)(rA + i*16*32);
    #pragma unroll
    for (int i=0;i<4;++i) bfr[i] = *(const short8*)(rB + i*16*32);
    #pragma unroll
    for (int mf=0;mf<4;++mf)
      #pragma unroll
      for (int nf=0;nf<4;++nf)
        acc[mf][nf] = __builtin_amdgcn_mfma_f32_16x16x32_bf16(af[mf], bfr[nf], acc[mf][nf], 0,0,0);
    cur = (cur==2) ? 0 : cur+1;
  }

  #pragma unroll
  for (int mf=0;mf<4;++mf){
    long mbase = mt*128 + wm*64 + mf*16 + quad*4;
    #pragma unroll
    for (int nf=0;nf<4;++nf){
      int col = nt*128 + wn*64 + nf*16 + l16;
      float bv = bias ? bias[col] : 0.f;
      #pragma unroll
      for (int r=0;r<4;++r){
        float v = acc[mf][nf][r] + bv;
        long m = mbase + r;
        if (outF) outF[m*ldo + col] = v;
        if (outB) outB[m*ldob + col] = f2bf(v);
      }
    }
  }
}

// ---------------------------------------------------------------------------
// Compacted preds GEMM (same 3-buffer pipelined structure). K=512.
// ---------------------------------------------------------------------------
__global__ __launch_bounds__(256) void gemm_preds(
    const unsigned short* __restrict__ A,
    const unsigned short* __restrict__ B,
    const float* __restrict__ bias,
    const int* __restrict__ rs,
    const int* __restrict__ trow, const int* __restrict__ brow,
    float* __restrict__ out)
{
  __shared__ unsigned short As[3][128*32];
  __shared__ unsigned short Bs[3][128*32];
  int nt = blockIdx.x % 79, mt = blockIdx.x / 79;
  int NR = rs[T_];
  if (mt*128 >= NR) return;
  int tid = threadIdx.x, wave = tid >> 6, lane = tid & 63;
  int quad = lane >> 4, l16 = lane & 15;

  const unsigned short* ga = A + (size_t)(mt*128 + wave*32 + (lane>>2))*D_ + (lane&3)*8;
  const unsigned short* gb = B + (size_t)(nt*128 + wave*32 + (lane>>2))*D_ + (lane&3)*8;

  int wm = wave >> 1, wn = wave & 1;

  auto STAGE = [&](int buf, int kk){
    unsigned short* la = &As[buf][wave*1024];
    unsigned short* lb = &Bs[buf][wave*1024];
    glds16(ga + kk,                 la);
    glds16(ga + kk + (size_t)16*D_, la + 512);
    glds16(gb + kk,                 lb);
    glds16(gb + kk + (size_t)16*D_, lb + 512);
  };

  f32x4 acc[4][4];
  #pragma unroll
  for (int i=0;i<4;++i)
    #pragma unroll
    for (int j=0;j<4;++j) acc[i][j] = (f32x4){0.f,0.f,0.f,0.f};

  STAGE(0, 0);
  STAGE(1, 32);
  int cur = 0;
  for (int k=0; k<D_; k+=32){
    if (k+32 < D_) asm volatile("s_waitcnt vmcnt(4)" ::: "memory");
    else           asm volatile("s_waitcnt vmcnt(0)" ::: "memory");
    __builtin_amdgcn_s_barrier();
    __builtin_amdgcn_sched_barrier(0);
    if (k+64 < D_) STAGE(cur==0 ? 2 : (cur==1 ? 0 : 1), k+64);
    const unsigned short* rA = &As[cur][(wm*64 + l16)*32 + quad*8];
    const unsigned short* rB = &Bs[cur][(wn*64 + l16)*32 + quad*8];
    short8 af[4], bfr[4];
    #pragma unroll
    for (int i=0;i<4;++i) af[i]  = *(const short8*)(rA + i*16*32);
    #pragma unroll
    for (int i=0;i<4;++i) bfr[i] = *(const short8*)(rB + i*16*32);
    #pragma unroll
    for (int mf=0;mf<4;++mf)
      #pragma unroll
      for (int nf=0;nf<4;++nf)
        acc[mf][nf] = __builtin_amdgcn_mfma_f32_16x16x32_bf16(af[mf], bfr[nf], acc[mf][nf], 0,0,0);
    cur = (cur==2) ? 0 : cur+1;
  }

  #pragma unroll
  for (int mf=0;mf<4;++mf){
    int mbase = mt*128 + wm*64 + mf*16 + quad*4;
    #pragma unroll
    for (int nf=0;nf<4;++nf){
      int col = nt*128 + wn*64 + nf*16 + l16;
      if (col >= V_) continue;
      float bv = bias[col];
      #pragma unroll
      for (int r=0;r<4;++r){
        int row = mbase + r;
        if (row >= NR) continue;
        int tt = trow[row], bb = brow[row];
        out[(size_t)(bb*T_ + tt)*V_ + col] = acc[mf][nf][r] + bv;
      }
    }
  }
}

// ---------------------------------------------------------------------------
// Per-step attention, active-prefix early exit.
// awe pass: 4 p-groups x 128 threads x uint4 (8 cols) -> 49 wide loads per
// thread (vs 196 narrow), 8-col ILP, LDS combine across groups.
// ---------------------------------------------------------------------------
__global__ __launch_bounds__(512) void att_step(
    const float* __restrict__ h,
    const unsigned short* __restrict__ WdaT,     // [D][A] bf16 (transposed)
    const float* __restrict__ bda,
    const unsigned short* __restrict__ att1,     // [B*P, A] bf16
    const float* __restrict__ wfull, const float* __restrict__ bfull,
    const unsigned short* __restrict__ enc_bf,   // [B,P,ENC] bf16
    const int* __restrict__ actv, int t,
    unsigned short* __restrict__ awe_bf,         // [B,ENC]
    float* __restrict__ out_alpha, long ldo)
{
  __shared__ float hs[D_];
  __shared__ float att2p[1024];
  __shared__ float att2s[A_];
  __shared__ float wfs[A_];
  __shared__ float als[256];
  __shared__ float red[16];
  __shared__ float awred[3*1160];   // padded stride 9 -> no bank conflict

  int bid = blockIdx.x, tid = threadIdx.x;
  int wave = tid >> 6, lane = tid & 63;
  int b = bid >> 1, j = bid & 1;

  if (b >= actv[t]){               // inactive: alphas zero, awe unused
    if (j == 0 && tid < P_) out_alpha[(size_t)b*ldo + tid] = 0.f;
    return;
  }

  if (tid < 128){
    ((float4*)wfs)[tid] = ((const float4*)wfull)[tid];
    ((float4*)hs)[tid]  = ((const float4*)(h + (size_t)b*D_))[tid];
  }
  __syncthreads();

  // att2 = h @ Wda^T via WdaT[k][a]: split-K over thread halves, 2 cols/thr
  {
    int half = tid >> 8, ap = tid & 255;
    const unsigned int* wp = (const unsigned int*)WdaT + (size_t)half*256*256 + ap;
    const float* hh = hs + half*256;
    float s0 = 0.f, s1 = 0.f;
    #pragma unroll 16
    for (int k=0;k<256;++k){
      unsigned int v = wp[(size_t)k*256];
      float hk = hh[k];
      s0 = fmaf(bf2f((unsigned short)(v & 0xffffu)), hk, s0);
      s1 = fmaf(bf2f((unsigned short)(v >> 16)),     hk, s1);
    }
    att2p[half*512 + ap*2]     = s0;
    att2p[half*512 + ap*2 + 1] = s1;
  }
  __syncthreads();
  if (tid < A_) att2s[tid] = att2p[tid] + att2p[512 + tid] + bda[tid];
  __syncthreads();

  // e[p] = relu(att1[p]+att2) . wfull  (8 waves over P rows)
  for (int p = wave; p < P_; p += 8){
    short8 v = *(const short8*)(att1 + ((size_t)(b*P_ + p))*A_ + lane*8);
    float4 a20 = *(const float4*)(att2s + lane*8);
    float4 a21 = *(const float4*)(att2s + lane*8 + 4);
    float4 wf0 = *(const float4*)(wfs + lane*8);
    float4 wf1 = *(const float4*)(wfs + lane*8 + 4);
    float s = 0.f;
    s += fmaxf(bf2f((unsigned short)v[0]) + a20.x, 0.f) * wf0.x;
    s += fmaxf(bf2f((unsigned short)v[1]) + a20.y, 0.f) * wf0.y;
    s += fmaxf(bf2f((unsigned short)v[2]) + a20.z, 0.f) * wf0.z;
    s += fmaxf(bf2f((unsigned short)v[3]) + a20.w, 0.f) * wf0.w;
    s += fmaxf(bf2f((unsigned short)v[4]) + a21.x, 0.f) * wf1.x;
    s += fmaxf(bf2f((unsigned short)v[5]) + a21.y, 0.f) * wf1.y;
    s += fmaxf(bf2f((unsigned short)v[6]) + a21.z, 0.f) * wf1.z;
    s += fmaxf(bf2f((unsigned short)v[7]) + a21.w, 0.f) * wf1.w;
    #pragma unroll
    for (int off=32; off; off>>=1) s += __shfl_xor(s, off, 64);
    if (lane == 0) als[p] = s + bfull[0];
  }
  __syncthreads();

  // softmax over 196
  float ev = (tid < P_) ? als[tid] : -1e30f;
  float mx = ev;
  #pragma unroll
  for (int off=32; off; off>>=1) mx = fmaxf(mx, __shfl_xor(mx, off, 64));
  if (lane == 0) red[wave] = mx;
  __syncthreads();
  float bmax = fmaxf(fmaxf(fmaxf(red[0],red[1]), fmaxf(red[2],red[3])),
                     fmaxf(fmaxf(red[4],red[5]), fmaxf(red[6],red[7])));
  float ex = (tid < P_) ? __expf(ev - bmax) : 0.f;
  float sm = ex;
  #pragma unroll
  for (int off=32; off; off>>=1) sm += __shfl_xor(sm, off, 64);
  if (lane == 0) red[8 + wave] = sm;
  __syncthreads();
  float inv = 1.f / (red[8]+red[9]+red[10]+red[11]+red[12]+red[13]+red[14]+red[15]);
  if (tid < P_){
    float alpha = ex * inv;
    als[tid] = alpha;
    if (j == 0) out_alpha[(size_t)b*ldo + tid] = alpha;
  }
  __syncthreads();

  // awe = alpha . enc, column-half j; 4 p-groups x 128 threads x uint4
  {
    int sub = tid >> 7, ti = tid & 127;
    const uint4* ep = (const uint4*)enc_bf + (size_t)b*P_*256 + j*128 + ti;
    float a8[8];
    #pragma unroll
    for (int i=0;i<8;++i) a8[i] = 0.f;
    #pragma unroll 8
    for (int pp=0; pp<49; ++pp){
      int p = sub + pp*4;
      uint4 v = ep[(size_t)p*256];
      float al = als[p];
      a8[0] = fmaf(bf2f((unsigned short)(v.x & 0xffffu)), al, a8[0]);
      a8[1] = fmaf(bf2f((unsigned short)(v.x >> 16)),     al, a8[1]);
      a8[2] = fmaf(bf2f((unsigned short)(v.y & 0xffffu)), al, a8[2]);
      a8[3] = fmaf(bf2f((unsigned short)(v.y >> 16)),     al, a8[3]);
      a8[4] = fmaf(bf2f((unsigned short)(v.z & 0xffffu)), al, a8[4]);
      a8[5] = fmaf(bf2f((unsigned short)(v.z >> 16)),     al, a8[5]);
      a8[6] = fmaf(bf2f((unsigned short)(v.w & 0xffffu)), al, a8[6]);
      a8[7] = fmaf(bf2f((unsigned short)(v.w >> 16)),     al, a8[7]);
    }
    if (sub > 0){
      float* dst = &awred[(sub-1)*1160 + ti*9];
      #pragma unroll
      for (int i=0;i<8;++i) dst[i] = a8[i];
    }
    __syncthreads();
    if (sub == 0){
      #pragma unroll
      for (int w=0;w<3;++w){
        const float* src = &awred[w*1160 + ti*9];
        #pragma unroll
        for (int i=0;i<8;++i) a8[i] += src[i];
      }
      uint4 o;
      o.x = pack2(a8[0], a8[1]);
      o.y = pack2(a8[2], a8[3]);
      o.z = pack2(a8[4], a8[5]);
      o.w = pack2(a8[6], a8[7]);
      ((uint4*)awe_bf)[(size_t)b*256 + j*128 + ti] = o;
    }
  }
}

// ---------------------------------------------------------------------------
// Per-step gates GEMM + LSTM pointwise, active-prefix skipping.
// K-loop split into two uniform loops (Whh part / Wienc part) so the
// compiler can software-pipeline the global loads.
// ---------------------------------------------------------------------------
__global__ __launch_bounds__(512) void gates_step(
    const unsigned short* __restrict__ hbf,
    const unsigned short* __restrict__ Whh,
    const unsigned short* __restrict__ awe,
    const unsigned short* __restrict__ Wienc,
    const float* __restrict__ gates_pre,
    float* __restrict__ h, float* __restrict__ c,
    unsigned short* __restrict__ hbf_out,
    unsigned short* __restrict__ h_cmp,
    const int* __restrict__ lens,
    const int* __restrict__ actv, const int* __restrict__ rs, int t)
{
  __shared__ float reds[8*1024];   // 32 KB
  int bid = blockIdx.x;
  int nt = (bid & 7)*4 + ((bid >> 3) & 3);   // XCD-grouped nt
  int mt = bid >> 5;
  int tid = threadIdx.x, wave = tid >> 6, lane = tid & 63;
  int quad = lane >> 4, l16 = lane & 15;
  int m0 = mt*16;
  int nact = actv[t];

  if (m0 >= nact){
    if (tid < 256){
      int mi = tid >> 4, di = tid & 15;
      int idx = (m0 + mi)*512 + nt*16 + di;
      hbf_out[idx] = hbf[idx];
    }
    return;
  }

  int ks = wave*320, ke = ks + 320;      // Ktot = 512 + 2048 over 8 waves
  f32x4 acc[4];
  #pragma unroll
  for (int f=0;f<4;++f) acc[f] = (f32x4){0.f,0.f,0.f,0.f};

  // part 1: Whh (kk in [ks, min(ke,512)))
  int e1 = ke < 512 ? ke : 512;
  #pragma unroll 2
  for (int kk=ks; kk<e1; kk+=32){
    short8 a = *(const short8*)(hbf + (size_t)(m0 + l16)*512 + kk + quad*8);
    #pragma unroll
    for (int f=0;f<4;++f){
      short8 bb = *(const short8*)(Whh + (size_t)(nt*16 + f*512 + l16)*512 + kk + quad*8);
      acc[f] = __builtin_amdgcn_mfma_f32_16x16x32_bf16(a, bb, acc[f], 0,0,0);
    }
  }
  // part 2: Wienc (k in [max(ks,512)-512, ke-512))
  int s2 = ks > 512 ? ks - 512 : 0;
  int e2 = ke - 512;
  #pragma unroll 2
  for (int k=s2; k<e2; k+=32){
    short8 a = *(const short8*)(awe + (size_t)(m0 + l16)*2048 + k + quad*8);
    #pragma unroll
    for (int f=0;f<4;++f){
      short8 bb = *(const short8*)(Wienc + (size_t)(nt*16 + f*512 + l16)*2048 + k + quad*8);
      acc[f] = __builtin_amdgcn_mfma_f32_16x16x32_bf16(a, bb, acc[f], 0,0,0);
    }
  }

  {
    float* dst = &reds[wave*1024 + lane*16];
    #pragma unroll
    for (int f=0;f<4;++f) ((f32x4*)dst)[f] = acc[f];
  }
  __syncthreads();
  if (tid < 256){
    int mi = tid >> 4, di = tid & 15;
    int m = m0 + mi, d = nt*16 + di;
    int rl = ((mi>>2)*16 + di)*16 + (mi&3);   // lane*16 + r
    float g4[4];
    #pragma unroll
    for (int f=0;f<4;++f){
      float s = 0.f;
      #pragma unroll
      for (int w=0;w<8;++w) s += reds[w*1024 + rl + f*4];
      g4[f] = s;
    }
    const float* gp = gates_pre + ((size_t)m*T_ + t)*2048;
    float vi = g4[0] + gp[d];
    float vf = g4[1] + gp[512 + d];
    float vg = g4[2] + gp[1024 + d];
    float vo = g4[3] + gp[1536 + d];
    float si = 1.f/(1.f + __expf(-vi));
    float sf = 1.f/(1.f + __expf(-vf));
    float so = 1.f/(1.f + __expf(-vo));
    float tg = tanhf(vg);
    int idx = m*512 + d;
    float cn = sf*c[idx] + si*tg;
    float hn = so*tanhf(cn);
    bool act = m < nact;
    float h2 = act ? hn : h[idx];
    float c2 = act ? cn : c[idx];
    h[idx] = h2; c[idx] = c2;
    unsigned short hb = f2bf(h2);
    hbf_out[idx] = hb;
    if (act) h_cmp[(size_t)(rs[t] + m)*512 + d] = hb;
  }
}

// ---- active-prefix bookkeeping ----
__global__ __launch_bounds__(256) void calc_active(
    const int* __restrict__ lens, int* __restrict__ actv,
    int* __restrict__ rs, int* __restrict__ trow, int* __restrict__ brow)
{
  __shared__ int scnt[T_];
  __shared__ int srs[T_+1];
  int tid = threadIdx.x;
  if (tid < T_){
    int cnt = 0;
    for (int b=0;b<B_;++b) cnt += ((lens[b]-1) > tid) ? 1 : 0;
    scnt[tid] = cnt; actv[tid] = cnt;
  }
  __syncthreads();
  if (tid == 0){
    int s = 0;
    for (int t=0;t<T_;++t){ srs[t] = s; rs[t] = s; s += scnt[t]; }
    srs[T_] = s; rs[T_] = s;
  }
  __syncthreads();
  int NR = srs[T_];
  for (int r = tid; r < NR; r += 256){
    int t = 0;
    while (r >= srs[t+1]) ++t;
    trow[r] = t; brow[r] = r - srs[t];
  }
}

// zero preds rows for inactive (b,t)
__global__ __launch_bounds__(256) void zero_inactive(
    const int* __restrict__ lens, float* __restrict__ out)
{
  int bid = blockIdx.x;
  int b = bid / T_, t = bid - b*T_;
  if ((lens[b]-1) > t) return;
  float4* o = (float4*)(out + (size_t)(b*T_ + t)*V_);
  float4 z = {0.f,0.f,0.f,0.f};
  for (int i = threadIdx.x; i < V_/4; i += 256) o[i] = z;
}

// ---- one-time helpers ----
__global__ __launch_bounds__(256) void enc_cvt_mean(
    const float* __restrict__ enc, unsigned short* __restrict__ enc_bf,
    unsigned short* __restrict__ mean_bf)
{
  int b = blockIdx.x >> 1;
  int c = (blockIdx.x & 1)*1024 + threadIdx.x*4;
  size_t base = (size_t)b*P_*ENCD + c;
  float s0=0.f,s1=0.f,s2=0.f,s3=0.f;
  for (int p=0; p<P_; p+=2){
    float4 v0 = *(const float4*)(enc + base + (size_t)(p+0)*ENCD);
    float4 v1 = *(const float4*)(enc + base + (size_t)(p+1)*ENCD);
    s0 += v0.x + v1.x; s1 += v0.y + v1.y; s2 += v0.z + v1.z; s3 += v0.w + v1.w;
    uint2 r0; r0.x = pack2(v0.x, v0.y); r0.y = pack2(v0.z, v0.w);
    uint2 r1; r1.x = pack2(v1.x, v1.y); r1.y = pack2(v1.z, v1.w);
    *(uint2*)(enc_bf + base + (size_t)(p+0)*ENCD) = r0;
    *(uint2*)(enc_bf + base + (size_t)(p+1)*ENCD) = r1;
  }
  const float is = 1.f/196.f;
  uint2 m; m.x = pack2(s0*is, s1*is); m.y = pack2(s2*is, s3*is);
  *(uint2*)(mean_bf + (size_t)b*ENCD + c) = m;
}

__global__ __launch_bounds__(256) void cvt_bf16(
    const float* __restrict__ in, unsigned short* __restrict__ out, int n4)
{
  int i = blockIdx.x*256 + threadIdx.x;
  if (i < n4){
    float4 v = ((const float4*)in)[i];
    uint2 o; o.x = pack2(v.x, v.y); o.y = pack2(v.z, v.w);
    ((uint2*)out)[i] = o;
  }
}

__global__ __launch_bounds__(256) void cvt_T_512(
    const float* __restrict__ W, unsigned short* __restrict__ WT)
{
  int a = blockIdx.x;
  for (int k = threadIdx.x; k < 512; k += 256)
    WT[(size_t)k*512 + a] = f2bf(W[(size_t)a*512 + k]);
}

__global__ __launch_bounds__(256) void split_wih(
    const float* __restrict__ W, unsigned short* __restrict__ Wemb,
    unsigned short* __restrict__ Wenc)
{
  int j = blockIdx.x;
  for (int k4 = threadIdx.x; k4 < 640; k4 += 256){
    float4 v = *(const float4*)(W + (size_t)j*2560 + k4*4);
    uint2 o; o.x = pack2(v.x, v.y); o.y = pack2(v.z, v.w);
    if (k4 < 128) *(uint2*)(Wemb + (size_t)j*512  + k4*4)        = o;
    else          *(uint2*)(Wenc + (size_t)j*2048 + (k4-128)*4)  = o;
  }
}

__global__ void add_bias2(const float* __restrict__ a, const float* __restrict__ b,
                          float* __restrict__ out, int n)
{
  int i = blockIdx.x*256 + threadIdx.x;
  if (i < n) out[i] = a[i] + b[i];
}

__global__ __launch_bounds__(128) void gather_emb(
    const int* __restrict__ caps, const float* __restrict__ E,
    unsigned short* __restrict__ X)
{
  int r = blockIdx.x;
  int b = r / T_, t = r - b*T_;
  int tok = caps[b*L_ + t];
  int c = threadIdx.x*4;
  float4 v = *(const float4*)(E + (size_t)tok*E_ + c);
  uint2 o; o.x = pack2(v.x, v.y); o.y = pack2(v.z, v.w);
  *(uint2*)(X + (size_t)r*E_ + c) = o;
}

// ---------------------------------------------------------------------------
extern "C" void kernel_launch(void* const* d_in, const int* in_sizes, int n_in,
                              void* d_out, int out_size, void* d_ws, size_t ws_size,
                              hipStream_t stream)
{
  const float* enc   = (const float*)d_in[0];
  const int*   caps  = (const int*)d_in[1];
  const int*   lens  = (const int*)d_in[2];
  const float* Eemb  = (const float*)d_in[3];
  const float* Wea   = (const float*)d_in[4];
  const float* bea   = (const float*)d_in[5];
  const float* Wda   = (const float*)d_in[6];
  const float* bda   = (const float*)d_in[7];
  const float* wfull = (const float*)d_in[8];
  const float* bfull = (const float*)d_in[9];
  const float* Wih0  = (const float*)d_in[10];
  const float* bih0  = (const float*)d_in[11];
  const float* Wic0  = (const float*)d_in[12];
  const float* bic0  = (const float*)d_in[13];
  const float* Wih   = (const float*)d_in[14];
  const float* bih   = (const float*)d_in[15];
  const float* Whh   = (const float*)d_in[16];
  const float* bhh   = (const float*)d_in[17];
  const float* Wfc   = (const float*)d_in[18];
  const float* bfc   = (const float*)d_in[19];

  char* wsp = (char*)d_ws;
  auto carve = [&](size_t bytes) -> char* {
    char* p = wsp; wsp += (bytes + 255) & ~(size_t)255; return p;
  };
  unsigned short* enc_bf   = (unsigned short*)carve((size_t)B_*P_*ENCD*2);
  unsigned short* att1_bf  = (unsigned short*)carve((size_t)B_*P_*A_*2);
  unsigned short* mean_bf  = (unsigned short*)carve((size_t)B_*ENCD*2);
  float*          gates_pre= (float*)carve((size_t)B_*T_*2048*4);
  unsigned short* X_emb    = (unsigned short*)carve((size_t)B_*T_*E_*2);
  unsigned short* Wea_bf   = (unsigned short*)carve((size_t)A_*ENCD*2);
  unsigned short* WdaT_bf  = (unsigned short*)carve((size_t)A_*D_*2);
  unsigned short* Wh0_bf   = (unsigned short*)carve((size_t)D_*ENCD*2);
  unsigned short* Wc0_bf   = (unsigned short*)carve((size_t)D_*ENCD*2);
  unsigned short* Whh_bf   = (unsigned short*)carve((size_t)2048*D_*2);
  unsigned short* Wie_bf   = (unsigned short*)carve((size_t)2048*E_*2);
  unsigned short* Wienc_bf = (unsigned short*)carve((size_t)2048*ENCD*2);
  unsigned short* Wfc_bf   = (unsigned short*)carve((size_t)VPAD*D_*2);
  float*          bias_ifgo= (float*)carve((size_t)2048*4);
  float*          h        = (float*)carve((size_t)B_*D_*4);
  float*          c        = (float*)carve((size_t)B_*D_*4);
  unsigned short* h_bf_all = (unsigned short*)carve((size_t)(T_+1)*B_*D_*2);
  unsigned short* h_cmp    = (unsigned short*)carve((size_t)T_*B_*D_*2);
  unsigned short* awe_bf   = (unsigned short*)carve((size_t)B_*ENCD*2);
  int*            actv     = (int*)carve(64*4);
  int*            rs       = (int*)carve(64*4);
  int*            trow     = (int*)carve((size_t)T_*B_*4);
  int*            brow     = (int*)carve((size_t)T_*B_*4);

  float* out_preds  = (float*)d_out;                       // [B, T, V]
  float* out_alphas = (float*)d_out + (size_t)B_*T_*V_;    // [B, T, P]

  // ---- one-time conversions / bookkeeping ----
  calc_active<<<1, 256, 0, stream>>>(lens, actv, rs, trow, brow);
  zero_inactive<<<B_*T_, 256, 0, stream>>>(lens, out_preds);
  enc_cvt_mean<<<256, 256, 0, stream>>>(enc, enc_bf, mean_bf);
  cvt_bf16<<<1024, 256, 0, stream>>>(Wea,  Wea_bf, A_*ENCD/4);
  cvt_T_512<<<512, 256, 0, stream>>>(Wda, WdaT_bf);
  cvt_bf16<<<1024, 256, 0, stream>>>(Wih0, Wh0_bf, D_*ENCD/4);
  cvt_bf16<<<1024, 256, 0, stream>>>(Wic0, Wc0_bf, D_*ENCD/4);
  cvt_bf16<<<1024, 256, 0, stream>>>(Whh,  Whh_bf, 2048*D_/4);
  cvt_bf16<<<5000, 256, 0, stream>>>(Wfc,  Wfc_bf, V_*D_/4);
  split_wih<<<2048, 256, 0, stream>>>(Wih, Wie_bf, Wienc_bf);
  add_bias2<<<8, 256, 0, stream>>>(bih, bhh, bias_ifgo, 2048);
  gather_emb<<<B_*T_, 128, 0, stream>>>(caps, Eemb, X_emb);

  // ---- hoisted GEMMs ----
  gemm128<<<1*4, 256, 0, stream>>>(mean_bf, ENCD, Wh0_bf, ENCD, ENCD,
                                   bih0, h, D_, h_bf_all, D_, 4);          // h0 (slot 0)
  gemm128<<<1*4, 256, 0, stream>>>(mean_bf, ENCD, Wc0_bf, ENCD, ENCD,
                                   bic0, c, D_, (unsigned short*)0, 0, 4); // c0
  gemm128<<<196*4, 256, 0, stream>>>(enc_bf, ENCD, Wea_bf, ENCD, ENCD,
                                     bea, (float*)0, 0, att1_bf, A_, 4);   // att1
  gemm128<<<21*16, 256, 0, stream>>>(X_emb, E_, Wie_bf, E_, E_,
                                     bias_ifgo, gates_pre, 2048, (unsigned short*)0, 0, 16);

  // ---- decode loop: 2 kernels per step ----
  for (int t = 0; t < T_; ++t){
    att_step<<<2*B_, 512, 0, stream>>>(h, WdaT_bf, bda, att1_bf, wfull, bfull,
                                       enc_bf, actv, t, awe_bf,
                                       out_alphas + (size_t)t*P_, (long)T_*P_);
    gates_step<<<256, 512, 0, stream>>>(h_bf_all + (size_t)t*B_*D_, Whh_bf,
                                        awe_bf, Wienc_bf, gates_pre,
                                        h, c, h_bf_all + (size_t)(t+1)*B_*D_,
                                        h_cmp, lens, actv, rs, t);
  }

  // ---- compacted preds GEMM ----
  gemm_preds<<<21*79, 256, 0, stream>>>(h_cmp, Wfc_bf, bfc, rs, trow, brow,
                                        out_preds);
}

// Round 6
// 1692.049 us; speedup vs baseline: 2.9544x; 1.0191x over previous
//
#include <hip/hip_runtime.h>
#include <hip/hip_bf16.h>

#define B_  128
#define P_  196
#define ENCD 2048
#define A_  512
#define E_  512
#define D_  512
#define V_  10000
#define L_  22
#define T_  21
#define VPAD 10112   // 79*128

typedef __attribute__((ext_vector_type(8))) short short8;
typedef __attribute__((ext_vector_type(4))) float f32x4;

static __device__ __forceinline__ float bf2f(unsigned short u){
  union { unsigned int i; float f; } x; x.i = ((unsigned int)u) << 16; return x.f;
}
static __device__ __forceinline__ unsigned short f2bf(float f){
  union { float f; unsigned int i; } x; x.f = f;
  unsigned int r = x.i + 0x7fffu + ((x.i >> 16) & 1u);
  return (unsigned short)(r >> 16);
}
static __device__ __forceinline__ unsigned int pack2(float a, float b){
  return (unsigned int)f2bf(a) | ((unsigned int)f2bf(b) << 16);
}
static __device__ __forceinline__ void glds16(const void* g, void* l){
  __builtin_amdgcn_global_load_lds((const __attribute__((address_space(1))) void*)g,
                                   (__attribute__((address_space(3))) void*)l, 16, 0, 0);
}

// ---------------------------------------------------------------------------
// 256x128-tile GEMM (8 waves): C[M,N] = A[M,K] @ B[N,K]^T (+bias).
// 3-buffer LDS pipeline, counted vmcnt(3) (one tile = 3 glds per wave:
// 2 for the wave's 32 A-rows, 1 for its 16 B-rows). 2x MFMA per barrier
// vs the 128-tile: amortizes the fixed per-iteration latency.
// M%256==0, N%128==0, K%32==0.
// ---------------------------------------------------------------------------
__global__ __launch_bounds__(512, 4) void gemm256(
    const unsigned short* __restrict__ A, int lda,
    const unsigned short* __restrict__ B, int ldb, int K,
    const float* __restrict__ bias,
    unsigned short* __restrict__ outB, long ldob,
    int ntiles)
{
  __shared__ unsigned short As[3][256*32];   // 48 KB
  __shared__ unsigned short Bs[3][128*32];   // 24 KB
  int bid = blockIdx.x, nblk = gridDim.x;
  if ((nblk & 7) == 0){ int per = nblk >> 3; bid = (bid & 7)*per + (bid >> 3); }
  int nt = bid % ntiles, mt = bid / ntiles;
  int tid = threadIdx.x, wave = tid >> 6, lane = tid & 63;
  int quad = lane >> 4, l16 = lane & 15;

  const unsigned short* ga = A + (size_t)(mt*256 + wave*32 + (lane>>2))*lda + (lane&3)*8;
  const unsigned short* gb = B + (size_t)(nt*128 + wave*16 + (lane>>2))*ldb + (lane&3)*8;

  int wm = wave >> 1, wn = wave & 1;   // wm in [0,4), wn in [0,2)

  auto STAGE = [&](int buf, int kk){
    unsigned short* la = &As[buf][wave*1024];
    unsigned short* lb = &Bs[buf][wave*512];
    glds16(ga + kk,                  la);
    glds16(ga + kk + (size_t)16*lda, la + 512);
    glds16(gb + kk,                  lb);
  };

  f32x4 acc[4][4];
  #pragma unroll
  for (int i=0;i<4;++i)
    #pragma unroll
    for (int j=0;j<4;++j) acc[i][j] = (f32x4){0.f,0.f,0.f,0.f};

  STAGE(0, 0);            // K >= 64 required
  STAGE(1, 32);
  int cur = 0;
  for (int k=0; k<K; k+=32){
    if (k+32 < K) asm volatile("s_waitcnt vmcnt(3)" ::: "memory");
    else          asm volatile("s_waitcnt vmcnt(0)" ::: "memory");
    __builtin_amdgcn_s_barrier();
    __builtin_amdgcn_sched_barrier(0);
    if (k+64 < K) STAGE(cur==0 ? 2 : (cur==1 ? 0 : 1), k+64);
    const unsigned short* rA = &As[cur][(wm*64 + l16)*32 + quad*8];
    const unsigned short* rB = &Bs[cur][(wn*64 + l16)*32 + quad*8];
    short8 af[4], bfr[4];
    #pragma unroll
    for (int i=0;i<4;++i) af[i]  = *(const short8*)(rA + i*16*32);
    #pragma unroll
    for (int i=0;i<4;++i) bfr[i] = *(const short8*)(rB + i*16*32);
    #pragma unroll
    for (int mf=0;mf<4;++mf)
      #pragma unroll
      for (int nf=0;nf<4;++nf)
        acc[mf][nf] = __builtin_amdgcn_mfma_f32_16x16x32_bf16(af[mf], bfr[nf], acc[mf][nf], 0,0,0);
    cur = (cur==2) ? 0 : cur+1;
  }

  #pragma unroll
  for (int mf=0;mf<4;++mf){
    long mbase = mt*256 + wm*64 + mf*16 + quad*4;
    #pragma unroll
    for (int nf=0;nf<4;++nf){
      int col = nt*128 + wn*64 + nf*16 + l16;
      float bv = bias ? bias[col] : 0.f;
      #pragma unroll
      for (int r=0;r<4;++r)
        outB[(mbase + r)*ldob + col] = f2bf(acc[mf][nf][r] + bv);
    }
  }
}

// ---------------------------------------------------------------------------
// 128x128-tile GEMM: 3-buffer counted-vmcnt pipeline (kept for small M).
// ---------------------------------------------------------------------------
__global__ __launch_bounds__(256) void gemm128(
    const unsigned short* __restrict__ A, int lda,
    const unsigned short* __restrict__ B, int ldb, int K,
    const float* __restrict__ bias,
    float* __restrict__ outF, long ldo,
    unsigned short* __restrict__ outB, long ldob,
    int ntiles)
{
  __shared__ unsigned short As[3][128*32];
  __shared__ unsigned short Bs[3][128*32];
  int bid = blockIdx.x, nblk = gridDim.x;
  if ((nblk & 7) == 0){ int per = nblk >> 3; bid = (bid & 7)*per + (bid >> 3); }
  int nt = bid % ntiles, mt = bid / ntiles;
  int tid = threadIdx.x, wave = tid >> 6, lane = tid & 63;
  int quad = lane >> 4, l16 = lane & 15;

  const unsigned short* ga = A + (size_t)(mt*128 + wave*32 + (lane>>2))*lda + (lane&3)*8;
  const unsigned short* gb = B + (size_t)(nt*128 + wave*32 + (lane>>2))*ldb + (lane&3)*8;

  int wm = wave >> 1, wn = wave & 1;

  auto STAGE = [&](int buf, int kk){
    unsigned short* la = &As[buf][wave*1024];
    unsigned short* lb = &Bs[buf][wave*1024];
    glds16(ga + kk,                  la);
    glds16(ga + kk + (size_t)16*lda, la + 512);
    glds16(gb + kk,                  lb);
    glds16(gb + kk + (size_t)16*ldb, lb + 512);
  };

  f32x4 acc[4][4];
  #pragma unroll
  for (int i=0;i<4;++i)
    #pragma unroll
    for (int j=0;j<4;++j) acc[i][j] = (f32x4){0.f,0.f,0.f,0.f};

  STAGE(0, 0);            // K >= 64 for all callers
  STAGE(1, 32);
  int cur = 0;
  for (int k=0; k<K; k+=32){
    if (k+32 < K) asm volatile("s_waitcnt vmcnt(4)" ::: "memory");
    else          asm volatile("s_waitcnt vmcnt(0)" ::: "memory");
    __builtin_amdgcn_s_barrier();
    __builtin_amdgcn_sched_barrier(0);
    if (k+64 < K) STAGE(cur==0 ? 2 : (cur==1 ? 0 : 1), k+64);
    const unsigned short* rA = &As[cur][(wm*64 + l16)*32 + quad*8];
    const unsigned short* rB = &Bs[cur][(wn*64 + l16)*32 + quad*8];
    short8 af[4], bfr[4];
    #pragma unroll
    for (int i=0;i<4;++i) af[i]  = *(const short8*)(rA + i*16*32);
    #pragma unroll
    for (int i=0;i<4;++i) bfr[i] = *(const short8*)(rB + i*16*32);
    #pragma unroll
    for (int mf=0;mf<4;++mf)
      #pragma unroll
      for (int nf=0;nf<4;++nf)
        acc[mf][nf] = __builtin_amdgcn_mfma_f32_16x16x32_bf16(af[mf], bfr[nf], acc[mf][nf], 0,0,0);
    cur = (cur==2) ? 0 : cur+1;
  }

  #pragma unroll
  for (int mf=0;mf<4;++mf){
    long mbase = mt*128 + wm*64 + mf*16 + quad*4;
    #pragma unroll
    for (int nf=0;nf<4;++nf){
      int col = nt*128 + wn*64 + nf*16 + l16;
      float bv = bias ? bias[col] : 0.f;
      #pragma unroll
      for (int r=0;r<4;++r){
        float v = acc[mf][nf][r] + bv;
        long m = mbase + r;
        if (outF) outF[m*ldo + col] = v;
        if (outB) outB[m*ldob + col] = f2bf(v);
      }
    }
  }
}

// ---------------------------------------------------------------------------
// Compacted preds GEMM (3-buffer pipelined). K=512.
// ---------------------------------------------------------------------------
__global__ __launch_bounds__(256) void gemm_preds(
    const unsigned short* __restrict__ A,
    const unsigned short* __restrict__ B,
    const float* __restrict__ bias,
    const int* __restrict__ rs,
    const int* __restrict__ trow, const int* __restrict__ brow,
    float* __restrict__ out)
{
  __shared__ unsigned short As[3][128*32];
  __shared__ unsigned short Bs[3][128*32];
  int nt = blockIdx.x % 79, mt = blockIdx.x / 79;
  int NR = rs[T_];
  if (mt*128 >= NR) return;
  int tid = threadIdx.x, wave = tid >> 6, lane = tid & 63;
  int quad = lane >> 4, l16 = lane & 15;

  const unsigned short* ga = A + (size_t)(mt*128 + wave*32 + (lane>>2))*D_ + (lane&3)*8;
  const unsigned short* gb = B + (size_t)(nt*128 + wave*32 + (lane>>2))*D_ + (lane&3)*8;

  int wm = wave >> 1, wn = wave & 1;

  auto STAGE = [&](int buf, int kk){
    unsigned short* la = &As[buf][wave*1024];
    unsigned short* lb = &Bs[buf][wave*1024];
    glds16(ga + kk,                 la);
    glds16(ga + kk + (size_t)16*D_, la + 512);
    glds16(gb + kk,                 lb);
    glds16(gb + kk + (size_t)16*D_, lb + 512);
  };

  f32x4 acc[4][4];
  #pragma unroll
  for (int i=0;i<4;++i)
    #pragma unroll
    for (int j=0;j<4;++j) acc[i][j] = (f32x4){0.f,0.f,0.f,0.f};

  STAGE(0, 0);
  STAGE(1, 32);
  int cur = 0;
  for (int k=0; k<D_; k+=32){
    if (k+32 < D_) asm volatile("s_waitcnt vmcnt(4)" ::: "memory");
    else           asm volatile("s_waitcnt vmcnt(0)" ::: "memory");
    __builtin_amdgcn_s_barrier();
    __builtin_amdgcn_sched_barrier(0);
    if (k+64 < D_) STAGE(cur==0 ? 2 : (cur==1 ? 0 : 1), k+64);
    const unsigned short* rA = &As[cur][(wm*64 + l16)*32 + quad*8];
    const unsigned short* rB = &Bs[cur][(wn*64 + l16)*32 + quad*8];
    short8 af[4], bfr[4];
    #pragma unroll
    for (int i=0;i<4;++i) af[i]  = *(const short8*)(rA + i*16*32);
    #pragma unroll
    for (int i=0;i<4;++i) bfr[i] = *(const short8*)(rB + i*16*32);
    #pragma unroll
    for (int mf=0;mf<4;++mf)
      #pragma unroll
      for (int nf=0;nf<4;++nf)
        acc[mf][nf] = __builtin_amdgcn_mfma_f32_16x16x32_bf16(af[mf], bfr[nf], acc[mf][nf], 0,0,0);
    cur = (cur==2) ? 0 : cur+1;
  }

  #pragma unroll
  for (int mf=0;mf<4;++mf){
    int mbase = mt*128 + wm*64 + mf*16 + quad*4;
    #pragma unroll
    for (int nf=0;nf<4;++nf){
      int col = nt*128 + wn*64 + nf*16 + l16;
      if (col >= V_) continue;
      float bv = bias[col];
      #pragma unroll
      for (int r=0;r<4;++r){
        int row = mbase + r;
        if (row >= NR) continue;
        int tt = trow[row], bb = brow[row];
        out[(size_t)(bb*T_ + tt)*V_ + col] = acc[mf][nf][r] + bv;
      }
    }
  }
}

// ---------------------------------------------------------------------------
// Per-step attention, active-prefix early exit. (unchanged from round 5)
// ---------------------------------------------------------------------------
__global__ __launch_bounds__(512) void att_step(
    const float* __restrict__ h,
    const unsigned short* __restrict__ WdaT,     // [D][A] bf16 (transposed)
    const float* __restrict__ bda,
    const unsigned short* __restrict__ att1,     // [B*P, A] bf16
    const float* __restrict__ wfull, const float* __restrict__ bfull,
    const unsigned short* __restrict__ enc_bf,   // [B,P,ENC] bf16
    const int* __restrict__ actv, int t,
    unsigned short* __restrict__ awe_bf,         // [B,ENC]
    float* __restrict__ out_alpha, long ldo)
{
  __shared__ float hs[D_];
  __shared__ float att2p[1024];
  __shared__ float att2s[A_];
  __shared__ float wfs[A_];
  __shared__ float als[256];
  __shared__ float red[16];
  __shared__ float awred[3*1160];   // padded stride 9 -> no bank conflict

  int bid = blockIdx.x, tid = threadIdx.x;
  int wave = tid >> 6, lane = tid & 63;
  int b = bid >> 1, j = bid & 1;

  if (b >= actv[t]){               // inactive: alphas zero, awe unused
    if (j == 0 && tid < P_) out_alpha[(size_t)b*ldo + tid] = 0.f;
    return;
  }

  if (tid < 128){
    ((float4*)wfs)[tid] = ((const float4*)wfull)[tid];
    ((float4*)hs)[tid]  = ((const float4*)(h + (size_t)b*D_))[tid];
  }
  __syncthreads();

  // att2 = h @ Wda^T via WdaT[k][a]: split-K over thread halves, 2 cols/thr
  {
    int half = tid >> 8, ap = tid & 255;
    const unsigned int* wp = (const unsigned int*)WdaT + (size_t)half*256*256 + ap;
    const float* hh = hs + half*256;
    float s0 = 0.f, s1 = 0.f;
    #pragma unroll 16
    for (int k=0;k<256;++k){
      unsigned int v = wp[(size_t)k*256];
      float hk = hh[k];
      s0 = fmaf(bf2f((unsigned short)(v & 0xffffu)), hk, s0);
      s1 = fmaf(bf2f((unsigned short)(v >> 16)),     hk, s1);
    }
    att2p[half*512 + ap*2]     = s0;
    att2p[half*512 + ap*2 + 1] = s1;
  }
  __syncthreads();
  if (tid < A_) att2s[tid] = att2p[tid] + att2p[512 + tid] + bda[tid];
  __syncthreads();

  // e[p] = relu(att1[p]+att2) . wfull  (8 waves over P rows)
  for (int p = wave; p < P_; p += 8){
    short8 v = *(const short8*)(att1 + ((size_t)(b*P_ + p))*A_ + lane*8);
    float4 a20 = *(const float4*)(att2s + lane*8);
    float4 a21 = *(const float4*)(att2s + lane*8 + 4);
    float4 wf0 = *(const float4*)(wfs + lane*8);
    float4 wf1 = *(const float4*)(wfs + lane*8 + 4);
    float s = 0.f;
    s += fmaxf(bf2f((unsigned short)v[0]) + a20.x, 0.f) * wf0.x;
    s += fmaxf(bf2f((unsigned short)v[1]) + a20.y, 0.f) * wf0.y;
    s += fmaxf(bf2f((unsigned short)v[2]) + a20.z, 0.f) * wf0.z;
    s += fmaxf(bf2f((unsigned short)v[3]) + a20.w, 0.f) * wf0.w;
    s += fmaxf(bf2f((unsigned short)v[4]) + a21.x, 0.f) * wf1.x;
    s += fmaxf(bf2f((unsigned short)v[5]) + a21.y, 0.f) * wf1.y;
    s += fmaxf(bf2f((unsigned short)v[6]) + a21.z, 0.f) * wf1.z;
    s += fmaxf(bf2f((unsigned short)v[7]) + a21.w, 0.f) * wf1.w;
    #pragma unroll
    for (int off=32; off; off>>=1) s += __shfl_xor(s, off, 64);
    if (lane == 0) als[p] = s + bfull[0];
  }
  __syncthreads();

  // softmax over 196
  float ev = (tid < P_) ? als[tid] : -1e30f;
  float mx = ev;
  #pragma unroll
  for (int off=32; off; off>>=1) mx = fmaxf(mx, __shfl_xor(mx, off, 64));
  if (lane == 0) red[wave] = mx;
  __syncthreads();
  float bmax = fmaxf(fmaxf(fmaxf(red[0],red[1]), fmaxf(red[2],red[3])),
                     fmaxf(fmaxf(red[4],red[5]), fmaxf(red[6],red[7])));
  float ex = (tid < P_) ? __expf(ev - bmax) : 0.f;
  float sm = ex;
  #pragma unroll
  for (int off=32; off; off>>=1) sm += __shfl_xor(sm, off, 64);
  if (lane == 0) red[8 + wave] = sm;
  __syncthreads();
  float inv = 1.f / (red[8]+red[9]+red[10]+red[11]+red[12]+red[13]+red[14]+red[15]);
  if (tid < P_){
    float alpha = ex * inv;
    als[tid] = alpha;
    if (j == 0) out_alpha[(size_t)b*ldo + tid] = alpha;
  }
  __syncthreads();

  // awe = alpha . enc, column-half j; 4 p-groups x 128 threads x uint4
  {
    int sub = tid >> 7, ti = tid & 127;
    const uint4* ep = (const uint4*)enc_bf + (size_t)b*P_*256 + j*128 + ti;
    float a8[8];
    #pragma unroll
    for (int i=0;i<8;++i) a8[i] = 0.f;
    #pragma unroll 8
    for (int pp=0; pp<49; ++pp){
      int p = sub + pp*4;
      uint4 v = ep[(size_t)p*256];
      float al = als[p];
      a8[0] = fmaf(bf2f((unsigned short)(v.x & 0xffffu)), al, a8[0]);
      a8[1] = fmaf(bf2f((unsigned short)(v.x >> 16)),     al, a8[1]);
      a8[2] = fmaf(bf2f((unsigned short)(v.y & 0xffffu)), al, a8[2]);
      a8[3] = fmaf(bf2f((unsigned short)(v.y >> 16)),     al, a8[3]);
      a8[4] = fmaf(bf2f((unsigned short)(v.z & 0xffffu)), al, a8[4]);
      a8[5] = fmaf(bf2f((unsigned short)(v.z >> 16)),     al, a8[5]);
      a8[6] = fmaf(bf2f((unsigned short)(v.w & 0xffffu)), al, a8[6]);
      a8[7] = fmaf(bf2f((unsigned short)(v.w >> 16)),     al, a8[7]);
    }
    if (sub > 0){
      float* dst = &awred[(sub-1)*1160 + ti*9];
      #pragma unroll
      for (int i=0;i<8;++i) dst[i] = a8[i];
    }
    __syncthreads();
    if (sub == 0){
      #pragma unroll
      for (int w=0;w<3;++w){
        const float* src = &awred[w*1160 + ti*9];
        #pragma unroll
        for (int i=0;i<8;++i) a8[i] += src[i];
      }
      uint4 o;
      o.x = pack2(a8[0], a8[1]);
      o.y = pack2(a8[2], a8[3]);
      o.z = pack2(a8[4], a8[5]);
      o.w = pack2(a8[6], a8[7]);
      ((uint4*)awe_bf)[(size_t)b*256 + j*128 + ti] = o;
    }
  }
}

// ---------------------------------------------------------------------------
// Per-step gates GEMM + LSTM pointwise. (unchanged from round 5)
// ---------------------------------------------------------------------------
__global__ __launch_bounds__(512) void gates_step(
    const unsigned short* __restrict__ hbf,
    const unsigned short* __restrict__ Whh,
    const unsigned short* __restrict__ awe,
    const unsigned short* __restrict__ Wienc,
    const float* __restrict__ gates_pre,
    float* __restrict__ h, float* __restrict__ c,
    unsigned short* __restrict__ hbf_out,
    unsigned short* __restrict__ h_cmp,
    const int* __restrict__ lens,
    const int* __restrict__ actv, const int* __restrict__ rs, int t)
{
  __shared__ float reds[8*1024];   // 32 KB
  int bid = blockIdx.x;
  int nt = (bid & 7)*4 + ((bid >> 3) & 3);   // XCD-grouped nt
  int mt = bid >> 5;
  int tid = threadIdx.x, wave = tid >> 6, lane = tid & 63;
  int quad = lane >> 4, l16 = lane & 15;
  int m0 = mt*16;
  int nact = actv[t];

  if (m0 >= nact){
    if (tid < 256){
      int mi = tid >> 4, di = tid & 15;
      int idx = (m0 + mi)*512 + nt*16 + di;
      hbf_out[idx] = hbf[idx];
    }
    return;
  }

  int ks = wave*320, ke = ks + 320;      // Ktot = 512 + 2048 over 8 waves
  f32x4 acc[4];
  #pragma unroll
  for (int f=0;f<4;++f) acc[f] = (f32x4){0.f,0.f,0.f,0.f};

  int e1 = ke < 512 ? ke : 512;
  #pragma unroll 2
  for (int kk=ks; kk<e1; kk+=32){
    short8 a = *(const short8*)(hbf + (size_t)(m0 + l16)*512 + kk + quad*8);
    #pragma unroll
    for (int f=0;f<4;++f){
      short8 bb = *(const short8*)(Whh + (size_t)(nt*16 + f*512 + l16)*512 + kk + quad*8);
      acc[f] = __builtin_amdgcn_mfma_f32_16x16x32_bf16(a, bb, acc[f], 0,0,0);
    }
  }
  int s2 = ks > 512 ? ks - 512 : 0;
  int e2 = ke - 512;
  #pragma unroll 2
  for (int k=s2; k<e2; k+=32){
    short8 a = *(const short8*)(awe + (size_t)(m0 + l16)*2048 + k + quad*8);
    #pragma unroll
    for (int f=0;f<4;++f){
      short8 bb = *(const short8*)(Wienc + (size_t)(nt*16 + f*512 + l16)*2048 + k + quad*8);
      acc[f] = __builtin_amdgcn_mfma_f32_16x16x32_bf16(a, bb, acc[f], 0,0,0);
    }
  }

  {
    float* dst = &reds[wave*1024 + lane*16];
    #pragma unroll
    for (int f=0;f<4;++f) ((f32x4*)dst)[f] = acc[f];
  }
  __syncthreads();
  if (tid < 256){
    int mi = tid >> 4, di = tid & 15;
    int m = m0 + mi, d = nt*16 + di;
    int rl = ((mi>>2)*16 + di)*16 + (mi&3);   // lane*16 + r
    float g4[4];
    #pragma unroll
    for (int f=0;f<4;++f){
      float s = 0.f;
      #pragma unroll
      for (int w=0;w<8;++w) s += reds[w*1024 + rl + f*4];
      g4[f] = s;
    }
    const float* gp = gates_pre + ((size_t)m*T_ + t)*2048;
    float vi = g4[0] + gp[d];
    float vf = g4[1] + gp[512 + d];
    float vg = g4[2] + gp[1024 + d];
    float vo = g4[3] + gp[1536 + d];
    float si = 1.f/(1.f + __expf(-vi));
    float sf = 1.f/(1.f + __expf(-vf));
    float so = 1.f/(1.f + __expf(-vo));
    float tg = tanhf(vg);
    int idx = m*512 + d;
    float cn = sf*c[idx] + si*tg;
    float hn = so*tanhf(cn);
    bool act = m < nact;
    float h2 = act ? hn : h[idx];
    float c2 = act ? cn : c[idx];
    h[idx] = h2; c[idx] = c2;
    unsigned short hb = f2bf(h2);
    hbf_out[idx] = hb;
    if (act) h_cmp[(size_t)(rs[t] + m)*512 + d] = hb;
  }
}

// ---- active-prefix bookkeeping ----
__global__ __launch_bounds__(256) void calc_active(
    const int* __restrict__ lens, int* __restrict__ actv,
    int* __restrict__ rs, int* __restrict__ trow, int* __restrict__ brow)
{
  __shared__ int scnt[T_];
  __shared__ int srs[T_+1];
  int tid = threadIdx.x;
  if (tid < T_){
    int cnt = 0;
    for (int b=0;b<B_;++b) cnt += ((lens[b]-1) > tid) ? 1 : 0;
    scnt[tid] = cnt; actv[tid] = cnt;
  }
  __syncthreads();
  if (tid == 0){
    int s = 0;
    for (int t=0;t<T_;++t){ srs[t] = s; rs[t] = s; s += scnt[t]; }
    srs[T_] = s; rs[T_] = s;
  }
  __syncthreads();
  int NR = srs[T_];
  for (int r = tid; r < NR; r += 256){
    int t = 0;
    while (r >= srs[t+1]) ++t;
    trow[r] = t; brow[r] = r - srs[t];
  }
}

// zero preds rows for inactive (b,t)
__global__ __launch_bounds__(256) void zero_inactive(
    const int* __restrict__ lens, float* __restrict__ out)
{
  int bid = blockIdx.x;
  int b = bid / T_, t = bid - b*T_;
  if ((lens[b]-1) > t) return;
  float4* o = (float4*)(out + (size_t)(b*T_ + t)*V_);
  float4 z = {0.f,0.f,0.f,0.f};
  for (int i = threadIdx.x; i < V_/4; i += 256) o[i] = z;
}

// ---- one-time helpers ----
__global__ __launch_bounds__(256) void enc_cvt_mean(
    const float* __restrict__ enc, unsigned short* __restrict__ enc_bf,
    unsigned short* __restrict__ mean_bf)
{
  int b = blockIdx.x >> 1;
  int c = (blockIdx.x & 1)*1024 + threadIdx.x*4;
  size_t base = (size_t)b*P_*ENCD + c;
  float s0=0.f,s1=0.f,s2=0.f,s3=0.f;
  for (int p=0; p<P_; p+=2){
    float4 v0 = *(const float4*)(enc + base + (size_t)(p+0)*ENCD);
    float4 v1 = *(const float4*)(enc + base + (size_t)(p+1)*ENCD);
    s0 += v0.x + v1.x; s1 += v0.y + v1.y; s2 += v0.z + v1.z; s3 += v0.w + v1.w;
    uint2 r0; r0.x = pack2(v0.x, v0.y); r0.y = pack2(v0.z, v0.w);
    uint2 r1; r1.x = pack2(v1.x, v1.y); r1.y = pack2(v1.z, v1.w);
    *(uint2*)(enc_bf + base + (size_t)(p+0)*ENCD) = r0;
    *(uint2*)(enc_bf + base + (size_t)(p+1)*ENCD) = r1;
  }
  const float is = 1.f/196.f;
  uint2 m; m.x = pack2(s0*is, s1*is); m.y = pack2(s2*is, s3*is);
  *(uint2*)(mean_bf + (size_t)b*ENCD + c) = m;
}

__global__ __launch_bounds__(256) void cvt_bf16(
    const float* __restrict__ in, unsigned short* __restrict__ out, int n4)
{
  int i = blockIdx.x*256 + threadIdx.x;
  if (i < n4){
    float4 v = ((const float4*)in)[i];
    uint2 o; o.x = pack2(v.x, v.y); o.y = pack2(v.z, v.w);
    ((uint2*)out)[i] = o;
  }
}

__global__ __launch_bounds__(256) void cvt_T_512(
    const float* __restrict__ W, unsigned short* __restrict__ WT)
{
  int a = blockIdx.x;
  for (int k = threadIdx.x; k < 512; k += 256)
    WT[(size_t)k*512 + a] = f2bf(W[(size_t)a*512 + k]);
}

__global__ __launch_bounds__(256) void split_wih(
    const float* __restrict__ W, unsigned short* __restrict__ Wemb,
    unsigned short* __restrict__ Wenc)
{
  int j = blockIdx.x;
  for (int k4 = threadIdx.x; k4 < 640; k4 += 256){
    float4 v = *(const float4*)(W + (size_t)j*2560 + k4*4);
    uint2 o; o.x = pack2(v.x, v.y); o.y = pack2(v.z, v.w);
    if (k4 < 128) *(uint2*)(Wemb + (size_t)j*512  + k4*4)        = o;
    else          *(uint2*)(Wenc + (size_t)j*2048 + (k4-128)*4)  = o;
  }
}

__global__ void add_bias2(const float* __restrict__ a, const float* __restrict__ b,
                          float* __restrict__ out, int n)
{
  int i = blockIdx.x*256 + threadIdx.x;
  if (i < n) out[i] = a[i] + b[i];
}

__global__ __launch_bounds__(128) void gather_emb(
    const int* __restrict__ caps, const float* __restrict__ E,
    unsigned short* __restrict__ X)
{
  int r = blockIdx.x;
  int b = r / T_, t = r - b*T_;
  int tok = caps[b*L_ + t];
  int c = threadIdx.x*4;
  float4 v = *(const float4*)(E + (size_t)tok*E_ + c);
  uint2 o; o.x = pack2(v.x, v.y); o.y = pack2(v.z, v.w);
  *(uint2*)(X + (size_t)r*E_ + c) = o;
}

// ---------------------------------------------------------------------------
extern "C" void kernel_launch(void* const* d_in, const int* in_sizes, int n_in,
                              void* d_out, int out_size, void* d_ws, size_t ws_size,
                              hipStream_t stream)
{
  const float* enc   = (const float*)d_in[0];
  const int*   caps  = (const int*)d_in[1];
  const int*   lens  = (const int*)d_in[2];
  const float* Eemb  = (const float*)d_in[3];
  const float* Wea   = (const float*)d_in[4];
  const float* bea   = (const float*)d_in[5];
  const float* Wda   = (const float*)d_in[6];
  const float* bda   = (const float*)d_in[7];
  const float* wfull = (const float*)d_in[8];
  const float* bfull = (const float*)d_in[9];
  const float* Wih0  = (const float*)d_in[10];
  const float* bih0  = (const float*)d_in[11];
  const float* Wic0  = (const float*)d_in[12];
  const float* bic0  = (const float*)d_in[13];
  const float* Wih   = (const float*)d_in[14];
  const float* bih   = (const float*)d_in[15];
  const float* Whh   = (const float*)d_in[16];
  const float* bhh   = (const float*)d_in[17];
  const float* Wfc   = (const float*)d_in[18];
  const float* bfc   = (const float*)d_in[19];

  char* wsp = (char*)d_ws;
  auto carve = [&](size_t bytes) -> char* {
    char* p = wsp; wsp += (bytes + 255) & ~(size_t)255; return p;
  };
  unsigned short* enc_bf   = (unsigned short*)carve((size_t)B_*P_*ENCD*2);
  unsigned short* att1_bf  = (unsigned short*)carve((size_t)B_*P_*A_*2);
  unsigned short* mean_bf  = (unsigned short*)carve((size_t)B_*ENCD*2);
  float*          gates_pre= (float*)carve((size_t)B_*T_*2048*4);
  unsigned short* X_emb    = (unsigned short*)carve((size_t)B_*T_*E_*2);
  unsigned short* Wea_bf   = (unsigned short*)carve((size_t)A_*ENCD*2);
  unsigned short* WdaT_bf  = (unsigned short*)carve((size_t)A_*D_*2);
  unsigned short* Wh0_bf   = (unsigned short*)carve((size_t)D_*ENCD*2);
  unsigned short* Wc0_bf   = (unsigned short*)carve((size_t)D_*ENCD*2);
  unsigned short* Whh_bf   = (unsigned short*)carve((size_t)2048*D_*2);
  unsigned short* Wie_bf   = (unsigned short*)carve((size_t)2048*E_*2);
  unsigned short* Wienc_bf = (unsigned short*)carve((size_t)2048*ENCD*2);
  unsigned short* Wfc_bf   = (unsigned short*)carve((size_t)VPAD*D_*2);
  float*          bias_ifgo= (float*)carve((size_t)2048*4);
  float*          h        = (float*)carve((size_t)B_*D_*4);
  float*          c        = (float*)carve((size_t)B_*D_*4);
  unsigned short* h_bf_all = (unsigned short*)carve((size_t)(T_+1)*B_*D_*2);
  unsigned short* h_cmp    = (unsigned short*)carve((size_t)T_*B_*D_*2);
  unsigned short* awe_bf   = (unsigned short*)carve((size_t)B_*ENCD*2);
  int*            actv     = (int*)carve(64*4);
  int*            rs       = (int*)carve(64*4);
  int*            trow     = (int*)carve((size_t)T_*B_*4);
  int*            brow     = (int*)carve((size_t)T_*B_*4);

  float* out_preds  = (float*)d_out;                       // [B, T, V]
  float* out_alphas = (float*)d_out + (size_t)B_*T_*V_;    // [B, T, P]

  // ---- one-time conversions / bookkeeping ----
  calc_active<<<1, 256, 0, stream>>>(lens, actv, rs, trow, brow);
  zero_inactive<<<B_*T_, 256, 0, stream>>>(lens, out_preds);
  enc_cvt_mean<<<256, 256, 0, stream>>>(enc, enc_bf, mean_bf);
  cvt_bf16<<<1024, 256, 0, stream>>>(Wea,  Wea_bf, A_*ENCD/4);
  cvt_T_512<<<512, 256, 0, stream>>>(Wda, WdaT_bf);
  cvt_bf16<<<1024, 256, 0, stream>>>(Wih0, Wh0_bf, D_*ENCD/4);
  cvt_bf16<<<1024, 256, 0, stream>>>(Wic0, Wc0_bf, D_*ENCD/4);
  cvt_bf16<<<1024, 256, 0, stream>>>(Whh,  Whh_bf, 2048*D_/4);
  cvt_bf16<<<5000, 256, 0, stream>>>(Wfc,  Wfc_bf, V_*D_/4);
  split_wih<<<2048, 256, 0, stream>>>(Wih, Wie_bf, Wienc_bf);
  add_bias2<<<8, 256, 0, stream>>>(bih, bhh, bias_ifgo, 2048);
  gather_emb<<<B_*T_, 128, 0, stream>>>(caps, Eemb, X_emb);

  // ---- hoisted GEMMs ----
  gemm128<<<1*4, 256, 0, stream>>>(mean_bf, ENCD, Wh0_bf, ENCD, ENCD,
                                   bih0, h, D_, h_bf_all, D_, 4);          // h0 (slot 0)
  gemm128<<<1*4, 256, 0, stream>>>(mean_bf, ENCD, Wc0_bf, ENCD, ENCD,
                                   bic0, c, D_, (unsigned short*)0, 0, 4); // c0
  gemm256<<<98*4, 512, 0, stream>>>(enc_bf, ENCD, Wea_bf, ENCD, ENCD,
                                    bea, att1_bf, A_, 4);                  // att1
  gemm128<<<21*16, 256, 0, stream>>>(X_emb, E_, Wie_bf, E_, E_,
                                     bias_ifgo, gates_pre, 2048, (unsigned short*)0, 0, 16);

  // ---- decode loop: 2 kernels per step ----
  for (int t = 0; t < T_; ++t){
    att_step<<<2*B_, 512, 0, stream>>>(h, WdaT_bf, bda, att1_bf, wfull, bfull,
                                       enc_bf, actv, t, awe_bf,
                                       out_alphas + (size_t)t*P_, (long)T_*P_);
    gates_step<<<256, 512, 0, stream>>>(h_bf_all + (size_t)t*B_*D_, Whh_bf,
                                        awe_bf, Wienc_bf, gates_pre,
                                        h, c, h_bf_all + (size_t)(t+1)*B_*D_,
                                        h_cmp, lens, actv, rs, t);
  }

  // ---- compacted preds GEMM ----
  gemm_preds<<<21*79, 256, 0, stream>>>(h_cmp, Wfc_bf, bfc, rs, trow, brow,
                                        out_preds);
}